// Round 10
// baseline (304.198 us; speedup 1.0000x reference)
//
#include <hip/hip_runtime.h>
#include <hip/hip_bf16.h>

#define DM 1024
#define DI 2048
#define DS 16
#define DC 4
#define BB 2
#define TT 1024
#define MM (BB*TT)   // 2048 rows
#define CCH 32       // scan chunks
#define LCH 32       // chunk length (TT/CCH)
#define PR 8         // rows per convproj block
#define SMW 36       // padded sm row (floats): 0=dt, 4..19=B, 20..35=C

typedef unsigned short u16;
typedef __attribute__((ext_vector_type(8))) short bf16x8;   // 8 bf16 (4 VGPRs)
typedef __attribute__((ext_vector_type(4))) float f32x4;    // 4 fp32 acc

#if __has_builtin(__builtin_amdgcn_exp2f)
#define EXP2F(x) __builtin_amdgcn_exp2f(x)
#else
#define EXP2F(x) exp2f(x)
#endif
#define L2E 1.44269504f

__device__ __forceinline__ float bu2f(u16 u) {
    union { unsigned int i; float f; } w; w.i = ((unsigned int)u) << 16; return w.f;
}
__device__ __forceinline__ u16 f2bu(float f) {  // round-to-nearest-even bf16
    union { float f; unsigned int u; } w; w.f = f;
    unsigned int r = w.u + 0x7fffu + ((w.u >> 16) & 1u);
    return (u16)(r >> 16);
}
// unpack element e (0..7) of a uint4 holding 8 bf16
__device__ __forceinline__ float upk(const uint4& v, int e) {
    unsigned int u;
    switch (e >> 1) { case 0: u = v.x; break; case 1: u = v.y; break;
                      case 2: u = v.z; break; default: u = v.w; }
    union { unsigned int i; float f; } w;
    w.i = (e & 1) ? (u & 0xffff0000u) : (u << 16);
    return w.f;
}

// ======= prep: LayerNorm (blocks 0..MM-1) + weight f32->bf16 (rest) ========
// Also zeroes the 16 decoupled-combine counters (visible to part1 via kernel
// boundary ordering).
#define F2B_BLOCKS 6210
__global__ __launch_bounds__(256) void prep_kernel(const float* __restrict__ x,
                                                   const float* __restrict__ gamma,
                                                   const float* __restrict__ beta,
                                                   u16* __restrict__ xn,
                                                   const float* __restrict__ Wi,
                                                   u16* __restrict__ Wi_b,
                                                   const float* __restrict__ Wo,
                                                   u16* __restrict__ Wo_b,
                                                   const float* __restrict__ Wx,
                                                   u16* __restrict__ Wx_b,
                                                   int* __restrict__ cnt) {
    const int tid = threadIdx.x;
    if (blockIdx.x == 0 && tid < BB * 8) cnt[tid] = 0;
    if (blockIdx.x >= MM) {
        const int n4W  = 2 * DI * DM / 4;
        const int n4Wo = DM * DI / 4;
        int i = (blockIdx.x - MM) * 256 + tid;
        const float* in; u16* out;
        if (i < n4W) { in = Wi; out = Wi_b; }
        else if (i < n4W + n4Wo) { in = Wo; out = Wo_b; i -= n4W; }
        else { in = Wx; out = Wx_b; i -= n4W + n4Wo; }
        float4 v = reinterpret_cast<const float4*>(in)[i];
        ushort4 o;
        o.x = f2bu(v.x); o.y = f2bu(v.y); o.z = f2bu(v.z); o.w = f2bu(v.w);
        reinterpret_cast<ushort4*>(out)[i] = o;
        return;
    }
    __shared__ float sbuf[8];
    const int row = blockIdx.x;
    float4 v = reinterpret_cast<const float4*>(x + (size_t)row * DM)[tid];

    float s = v.x + v.y + v.z + v.w;
    #pragma unroll
    for (int off = 32; off; off >>= 1) s += __shfl_down(s, off);
    if ((tid & 63) == 0) sbuf[tid >> 6] = s;
    __syncthreads();
    float mu = (sbuf[0] + sbuf[1] + sbuf[2] + sbuf[3]) * (1.0f / DM);
    __syncthreads();

    float d0 = v.x - mu, d1 = v.y - mu, d2 = v.z - mu, d3 = v.w - mu;
    float q = d0*d0 + d1*d1 + d2*d2 + d3*d3;
    #pragma unroll
    for (int off = 32; off; off >>= 1) q += __shfl_down(q, off);
    if ((tid & 63) == 0) sbuf[tid >> 6] = q;
    __syncthreads();
    float var = (sbuf[0] + sbuf[1] + sbuf[2] + sbuf[3]) * (1.0f / DM);
    float rstd = rsqrtf(var + 1e-5f);

    float4 g = reinterpret_cast<const float4*>(gamma)[tid];
    float4 b = reinterpret_cast<const float4*>(beta)[tid];
    ushort4 o;
    o.x = f2bu(d0 * rstd * g.x + b.x);
    o.y = f2bu(d1 * rstd * g.y + b.y);
    o.z = f2bu(d2 * rstd * g.z + b.z);
    o.w = f2bu(d3 * rstd * g.w + b.w);
    reinterpret_cast<ushort4*>(xn + (size_t)row * DM)[tid] = o;
}

// ========== MFMA GEMMs (NT), double-buffered, slot-XOR LDS swizzle =========
__device__ __forceinline__ void gl_lds(const u16* g, u16* lds) {
    __builtin_amdgcn_global_load_lds((const __attribute__((address_space(1))) void*)g,
                                     (__attribute__((address_space(3))) void*)lds,
                                     16, 0, 0);
}

// gemm1: 128x128 tile, BK=64 (two 32-k sub-tiles), 4 waves 2x2 (each 64x64).
// 512 blocks (2/CU), 64 KB LDS.
__global__ __launch_bounds__(256) void gemm1_mfma(const u16* __restrict__ A,
                                                  const u16* __restrict__ B,
                                                  u16* __restrict__ C,
                                                  int M, int N, int K) {
    __shared__ u16 As[2][2][128 * 32];   // [buf][kh] 32 KB
    __shared__ u16 Bs[2][2][128 * 32];   // 32 KB
    const int tid  = threadIdx.x;
    const int lane = tid & 63;
    const int w    = tid >> 6;
    const int wm   = (w >> 1) * 64, wn = (w & 1) * 64;
    const int m0   = blockIdx.y * 128, n0 = blockIdx.x * 128;

    const int srow = tid >> 2;           // 0..63
    const int sk   = (((tid & 3) ^ ((srow >> 1) & 3)) * 8);   // swizzled k-octet
    const u16* aP0 = A + (size_t)(m0 + srow) * K + sk;
    const u16* aP1 = aP0 + (size_t)64 * K;
    const u16* bP0 = B + (size_t)(n0 + srow) * K + sk;
    const u16* bP1 = bP0 + (size_t)64 * K;
    const int ldst = tid * 8;            // LINEAR dest, 16 B/thread

    const int fr = lane & 15, fq = (lane >> 4) * 8;

    #pragma unroll
    for (int kh = 0; kh < 2; kh++) {
        gl_lds(aP0 + kh * 32, &As[0][kh][ldst]); gl_lds(aP1 + kh * 32, &As[0][kh][2048 + ldst]);
        gl_lds(bP0 + kh * 32, &Bs[0][kh][ldst]); gl_lds(bP1 + kh * 32, &Bs[0][kh][2048 + ldst]);
    }
    __syncthreads();

    const int iters = K >> 6;            // 16
    f32x4 acc[4][4] = {};
    for (int it = 0; it < iters; it++) {
        const int cur = it & 1;
        const int kn = (it + 1) << 6;
        if (kn < K) {
            const int nb = cur ^ 1;
            #pragma unroll
            for (int kh = 0; kh < 2; kh++) {
                gl_lds(aP0 + kn + kh * 32, &As[nb][kh][ldst]);
                gl_lds(aP1 + kn + kh * 32, &As[nb][kh][2048 + ldst]);
                gl_lds(bP0 + kn + kh * 32, &Bs[nb][kh][ldst]);
                gl_lds(bP1 + kn + kh * 32, &Bs[nb][kh][2048 + ldst]);
            }
        }
        #pragma unroll
        for (int kh = 0; kh < 2; kh++) {
            bf16x8 af[4], bf[4];
            #pragma unroll
            for (int i = 0; i < 4; i++) {
                const int ra = wm + i * 16 + fr;
                af[i] = *reinterpret_cast<const bf16x8*>(
                    &As[cur][kh][ra * 32 + (fq ^ (((ra >> 1) & 3) << 3))]);
            }
            #pragma unroll
            for (int j = 0; j < 4; j++) {
                const int rb = wn + j * 16 + fr;
                bf[j] = *reinterpret_cast<const bf16x8*>(
                    &Bs[cur][kh][rb * 32 + (fq ^ (((rb >> 1) & 3) << 3))]);
            }
            #pragma unroll
            for (int i = 0; i < 4; i++)
                #pragma unroll
                for (int j = 0; j < 4; j++)
                    acc[i][j] = __builtin_amdgcn_mfma_f32_16x16x32_bf16(af[i], bf[j], acc[i][j], 0, 0, 0);
        }
        __syncthreads();
    }

    const int erow = (lane >> 4) * 4, ecol = lane & 15;
    #pragma unroll
    for (int i = 0; i < 4; i++)
        #pragma unroll
        for (int j = 0; j < 4; j++) {
            const int col = n0 + wn + j * 16 + ecol;
            #pragma unroll
            for (int r = 0; r < 4; r++) {
                const int row = m0 + wm + i * 16 + erow + r;
                C[(size_t)row * N + col] = f2bu(acc[i][j][r]);
            }
        }
}

// gemm2: 64x64 tile, BK=128 (four 32-k sub-tiles), 4 waves 2x2, +residual,
// fp32 out. 512 blocks (2/CU), 64 KB LDS. Same swizzle.
__global__ __launch_bounds__(256) void gemm2_mfma(const u16* __restrict__ A,
                                                  const u16* __restrict__ B,
                                                  float* __restrict__ C,
                                                  const float* __restrict__ resid,
                                                  int M, int N, int K) {
    __shared__ u16 As[2][4][64 * 32];   // 32 KB
    __shared__ u16 Bs[2][4][64 * 32];   // 32 KB
    const int tid  = threadIdx.x;
    const int lane = tid & 63;
    const int w    = tid >> 6;
    const int wm   = (w >> 1) * 32, wn = (w & 1) * 32;
    const int m0   = blockIdx.y * 64, n0 = blockIdx.x * 64;

    const int srow = tid >> 2;
    const int sk   = (((tid & 3) ^ ((srow >> 1) & 3)) * 8);
    const u16* aP = A + (size_t)(m0 + srow) * K + sk;
    const u16* bP = B + (size_t)(n0 + srow) * K + sk;
    const int ldst = tid * 8;

    const int fr = lane & 15, fq = (lane >> 4) * 8;

    #pragma unroll
    for (int kh = 0; kh < 4; kh++) {
        gl_lds(aP + kh * 32, &As[0][kh][ldst]);
        gl_lds(bP + kh * 32, &Bs[0][kh][ldst]);
    }
    __syncthreads();

    const int iters = K >> 7;            // 16
    f32x4 acc[2][2] = {};
    for (int it = 0; it < iters; it++) {
        const int cur = it & 1;
        const int kn = (it + 1) << 7;
        if (kn < K) {
            const int nb = cur ^ 1;
            #pragma unroll
            for (int kh = 0; kh < 4; kh++) {
                gl_lds(aP + kn + kh * 32, &As[nb][kh][ldst]);
                gl_lds(bP + kn + kh * 32, &Bs[nb][kh][ldst]);
            }
        }
        #pragma unroll
        for (int kh = 0; kh < 4; kh++) {
            bf16x8 af[2], bf[2];
            #pragma unroll
            for (int i = 0; i < 2; i++) {
                const int ra = wm + i * 16 + fr;
                af[i] = *reinterpret_cast<const bf16x8*>(
                    &As[cur][kh][ra * 32 + (fq ^ (((ra >> 1) & 3) << 3))]);
            }
            #pragma unroll
            for (int j = 0; j < 2; j++) {
                const int rb = wn + j * 16 + fr;
                bf[j] = *reinterpret_cast<const bf16x8*>(
                    &Bs[cur][kh][rb * 32 + (fq ^ (((rb >> 1) & 3) << 3))]);
            }
            #pragma unroll
            for (int i = 0; i < 2; i++)
                #pragma unroll
                for (int j = 0; j < 2; j++)
                    acc[i][j] = __builtin_amdgcn_mfma_f32_16x16x32_bf16(af[i], bf[j], acc[i][j], 0, 0, 0);
        }
        __syncthreads();
    }

    const int erow = (lane >> 4) * 4, ecol = lane & 15;
    #pragma unroll
    for (int i = 0; i < 2; i++)
        #pragma unroll
        for (int j = 0; j < 2; j++) {
            const int col = n0 + wn + j * 16 + ecol;
            #pragma unroll
            for (int r = 0; r < 4; r++) {
                const int row = m0 + wm + i * 16 + erow + r;
                C[(size_t)row * N + col] = acc[i][j][r] + resid[(size_t)row * N + col];
            }
        }
}

// ======= Fused depthwise conv(k=4) + SiLU + MFMA ssm projection ============
__global__ __launch_bounds__(256) void convproj_kernel(const u16* __restrict__ xz,
                                                       const float* __restrict__ cw,
                                                       const float* __restrict__ cb,
                                                       const u16* __restrict__ Wxb,
                                                       u16* __restrict__ xc,
                                                       float* __restrict__ ssm) {
    __shared__ u16 xs[64 * PR * 32];     // [kt][r][ko] 32 KB
    __shared__ float red[4][PR][48];     // 6 KB
    const int tid  = threadIdx.x;
    const int row0 = blockIdx.x * PR;
    const int t0   = row0 & (TT - 1);
    const int d0   = tid * 8;

    float4 w4[8];
    #pragma unroll
    for (int e = 0; e < 8; e++) w4[e] = reinterpret_cast<const float4*>(cw)[d0 + e];
    float bias[8];
    *reinterpret_cast<float4*>(&bias[0]) = reinterpret_cast<const float4*>(cb + d0)[0];
    *reinterpret_cast<float4*>(&bias[4]) = reinterpret_cast<const float4*>(cb + d0)[1];

    uint4 pk[PR + 3];
    #pragma unroll
    for (int j = 0; j < PR + 3; j++) {
        const int tr = t0 - 3 + j;
        if (tr >= 0)
            pk[j] = *reinterpret_cast<const uint4*>(xz + (size_t)(row0 - 3 + j) * (2 * DI) + d0);
        else
            pk[j] = make_uint4(0, 0, 0, 0);
    }

    const int kt_w = tid >> 2;
    const int ko_w = (tid & 3) * 8;
    #pragma unroll
    for (int r = 0; r < PR; r++) {
        u16 ob[8];
        #pragma unroll
        for (int e = 0; e < 8; e++) {
            float a = bias[e]
                    + upk(pk[r],     e) * w4[e].x
                    + upk(pk[r + 1], e) * w4[e].y
                    + upk(pk[r + 2], e) * w4[e].z
                    + upk(pk[r + 3], e) * w4[e].w;
            float sv = a / (1.0f + __expf(-a));
            ob[e] = f2bu(sv);
        }
        uint4 o;
        o.x = (unsigned)ob[0] | ((unsigned)ob[1] << 16);
        o.y = (unsigned)ob[2] | ((unsigned)ob[3] << 16);
        o.z = (unsigned)ob[4] | ((unsigned)ob[5] << 16);
        o.w = (unsigned)ob[6] | ((unsigned)ob[7] << 16);
        *reinterpret_cast<uint4*>(xc + (size_t)(row0 + r) * DI + d0) = o;
        *reinterpret_cast<uint4*>(&xs[kt_w * (PR * 32) + r * 32 + ko_w]) = o;
    }
    __syncthreads();

    const int lane = tid & 63, w = tid >> 6;
    const int fr = lane & 15, fq = (lane >> 4) * 8;
    const int kt0 = w * 16;
    const u16* b0p = Wxb + (size_t)(fr)      * DI + fq;
    const u16* b1p = Wxb + (size_t)(16 + fr) * DI + fq;
    const u16* b2p = Wxb + (size_t)32        * DI + fq;

    f32x4 acc0 = {}, acc1 = {}, acc2 = {};
    bf16x8 a_c = *reinterpret_cast<const bf16x8*>(&xs[kt0 * (PR * 32) + (fr & 7) * 32 + fq]);
    bf16x8 b0c = *reinterpret_cast<const bf16x8*>(b0p + (size_t)kt0 * 32);
    bf16x8 b1c = *reinterpret_cast<const bf16x8*>(b1p + (size_t)kt0 * 32);
    bf16x8 b2c = *reinterpret_cast<const bf16x8*>(b2p + (size_t)kt0 * 32);
    #pragma unroll
    for (int i = 0; i < 16; i++) {
        bf16x8 a_n, b0n, b1n, b2n;
        if (i < 15) {
            const int ktn = kt0 + i + 1;
            a_n = *reinterpret_cast<const bf16x8*>(&xs[ktn * (PR * 32) + (fr & 7) * 32 + fq]);
            b0n = *reinterpret_cast<const bf16x8*>(b0p + (size_t)ktn * 32);
            b1n = *reinterpret_cast<const bf16x8*>(b1p + (size_t)ktn * 32);
            b2n = *reinterpret_cast<const bf16x8*>(b2p + (size_t)ktn * 32);
        }
        acc0 = __builtin_amdgcn_mfma_f32_16x16x32_bf16(a_c, b0c, acc0, 0, 0, 0);
        acc1 = __builtin_amdgcn_mfma_f32_16x16x32_bf16(a_c, b1c, acc1, 0, 0, 0);
        acc2 = __builtin_amdgcn_mfma_f32_16x16x32_bf16(a_c, b2c, acc2, 0, 0, 0);
        if (i < 15) { a_c = a_n; b0c = b0n; b1c = b1n; b2c = b2n; }
    }
    const int erow = (lane >> 4) * 4, ecol = lane & 15;
    if (erow < PR) {
        #pragma unroll
        for (int r = 0; r < 4; r++) {
            red[w][erow + r][0 * 16 + ecol] = acc0[r];
            red[w][erow + r][1 * 16 + ecol] = acc1[r];
            red[w][erow + r][2 * 16 + ecol] = acc2[r];
        }
    }
    __syncthreads();

    // full coverage: all PR*33 = 264 cells via strided loop
    for (int idx = tid; idx < PR * 33; idx += 256) {
        const int rr = idx / 33, n = idx % 33;
        float s = red[0][rr][n] + red[1][rr][n] + red[2][rr][n] + red[3][rr][n];
        ssm[(size_t)(row0 + rr) * 33 + n] = s;
    }
}

// ======================= Chunked selective scan =============================
// part1: per-chunk scan -> F + Sdt; the LAST block per (b,dt8) group (device-
// scope atomic counter, CUB decoupled pattern) runs the inter-chunk combine
// in its tail: F[c] <- carry-in for chunk c (read-then-write, exact
// scan_combine semantics). Saves one kernel launch + boundary.
__global__ __launch_bounds__(256) void scan_part1(const float* __restrict__ ssm,
                                                  const u16* __restrict__ xcy,
                                                  const float* __restrict__ w_dt,
                                                  const float* __restrict__ b_dt,
                                                  const float* __restrict__ A_log,
                                                  float* __restrict__ F,
                                                  float* __restrict__ Sdt,
                                                  int* __restrict__ cnt) {
    __shared__ float sm[LCH * SMW];                // 4.6 KB padded
    __shared__ u16 xls[LCH * 256];                 // 16 KB
    __shared__ int lastFlag;
    const int tid = threadIdx.x;
    const int dt8 = blockIdx.x & 7;                // d-tile (DI/256 = 8)
    const int bc  = blockIdx.x >> 3;               // 0..63
    const int c   = bc & (CCH - 1);
    const int b   = bc >> 5;
    const int d   = dt8 * 256 + tid;

    const int base = ((b * TT) + c * LCH) * 33;
    for (int i = tid; i < LCH * 33; i += 256) {
        int t = i / 33, j = i % 33;                // slot: 0->0, j->j+3
        sm[t * SMW + (j == 0 ? 0 : j + 3)] = ssm[base + i];
    }
    const u16* xg = xcy + (size_t)(b * TT + c * LCH) * DI + dt8 * 256;
    for (int i = tid; i < LCH * 128; i += 256) {   // uint = 2 bf16
        int t = i >> 7, dp = i & 127;
        unsigned int v = *reinterpret_cast<const unsigned int*>(xg + (size_t)t * DI + dp * 2);
        *reinterpret_cast<unsigned int*>(&xls[t * 256 + dp * 2]) = v;
    }
    __syncthreads();

    float A2[DS], h[DS];
    float4 al[4];
    #pragma unroll
    for (int i = 0; i < 4; i++)
        al[i] = reinterpret_cast<const float4*>(A_log + (size_t)d * DS)[i];
    #pragma unroll
    for (int i = 0; i < 4; i++) {
        A2[4*i+0] = -__expf(al[i].x) * L2E;
        A2[4*i+1] = -__expf(al[i].y) * L2E;
        A2[4*i+2] = -__expf(al[i].z) * L2E;
        A2[4*i+3] = -__expf(al[i].w) * L2E;
    }
    #pragma unroll
    for (int n = 0; n < DS; n++) h[n] = 0.f;
    const float wdt = w_dt[d], bdt = b_dt[d];
    float sdt = 0.f;

    for (int t = 0; t < LCH; t++) {
        const float* sp = &sm[t * SMW];
        float Bv[DS];
        #pragma unroll
        for (int i = 0; i < 4; i++) {
            float4 bv = *reinterpret_cast<const float4*>(sp + 4 + 4 * i);
            Bv[4*i+0] = bv.x; Bv[4*i+1] = bv.y; Bv[4*i+2] = bv.z; Bv[4*i+3] = bv.w;
        }
        float pre = sp[0] * wdt + bdt;
        float dtv = (pre > 20.f) ? pre : __logf(1.f + __expf(pre));
        sdt += dtv;
        float xv = bu2f(xls[t * 256 + tid]);
        float u = dtv * xv;
        #pragma unroll
        for (int n = 0; n < DS; n++) h[n] = EXP2F(dtv * A2[n]) * h[n] + u * Bv[n];
    }
    const size_t fo = ((size_t)(b * CCH + c) * DI + d) * DS;
    #pragma unroll
    for (int n = 0; n < DS; n++) F[fo + n] = h[n];
    Sdt[(b * CCH + c) * DI + d] = sdt;

    // ---- decoupled last-arriver combine ----
    __threadfence();                               // publish F/Sdt (device scope)
    if (tid == 0) {
        int old = atomicAdd(&cnt[b * 8 + dt8], 1);
        lastFlag = (old == CCH - 1);
    }
    __syncthreads();
    if (lastFlag) {
        __threadfence();                           // order reads after counter
        float h2[DS];
        #pragma unroll
        for (int n = 0; n < DS; n++) h2[n] = 0.f;
        for (int cc = 0; cc < CCH; cc++) {
            const size_t o = ((size_t)(b * CCH + cc) * DI + d) * DS;
            float4 f0 = *reinterpret_cast<const float4*>(F + o);
            float4 f1 = *reinterpret_cast<const float4*>(F + o + 4);
            float4 f2 = *reinterpret_cast<const float4*>(F + o + 8);
            float4 f3 = *reinterpret_cast<const float4*>(F + o + 12);
            float sdtc = Sdt[(size_t)(b * CCH + cc) * DI + d];
            float fa[DS] = { f0.x, f0.y, f0.z, f0.w, f1.x, f1.y, f1.z, f1.w,
                             f2.x, f2.y, f2.z, f2.w, f3.x, f3.y, f3.z, f3.w };
            float hc[DS];
            #pragma unroll
            for (int n = 0; n < DS; n++) {
                hc[n] = h2[n];
                h2[n] = EXP2F(sdtc * A2[n]) * h2[n] + fa[n];
            }
            *reinterpret_cast<float4*>(F + o)      = make_float4(hc[0], hc[1], hc[2], hc[3]);
            *reinterpret_cast<float4*>(F + o + 4)  = make_float4(hc[4], hc[5], hc[6], hc[7]);
            *reinterpret_cast<float4*>(F + o + 8)  = make_float4(hc[8], hc[9], hc[10], hc[11]);
            *reinterpret_cast<float4*>(F + o + 12) = make_float4(hc[12], hc[13], hc[14], hc[15]);
        }
    }
}

// part2: final scan with carry-in (Hin = F, written by part1's last-arriver;
// kernel boundary guarantees visibility) + gate.
__global__ __launch_bounds__(256) void scan_part2(const float* __restrict__ ssm,
                                                  const u16* __restrict__ xz,
                                                  u16* __restrict__ xcy,
                                                  const float* __restrict__ w_dt,
                                                  const float* __restrict__ b_dt,
                                                  const float* __restrict__ A_log,
                                                  const float* __restrict__ Dp,
                                                  const float* __restrict__ Hin) {
    __shared__ float sm[LCH * SMW];
    __shared__ u16 xls[LCH * 256];
    const int tid = threadIdx.x;
    const int dt8 = blockIdx.x & 7;
    const int bc  = blockIdx.x >> 3;
    const int c   = bc & (CCH - 1);
    const int b   = bc >> 5;
    const int d   = dt8 * 256 + tid;

    const int base = ((b * TT) + c * LCH) * 33;
    for (int i = tid; i < LCH * 33; i += 256) {
        int t = i / 33, j = i % 33;
        sm[t * SMW + (j == 0 ? 0 : j + 3)] = ssm[base + i];
    }
    const u16* xg = xcy + (size_t)(b * TT + c * LCH) * DI + dt8 * 256;
    for (int i = tid; i < LCH * 128; i += 256) {
        int t = i >> 7, dp = i & 127;
        unsigned int v = *reinterpret_cast<const unsigned int*>(xg + (size_t)t * DI + dp * 2);
        *reinterpret_cast<unsigned int*>(&xls[t * 256 + dp * 2]) = v;
    }
    __syncthreads();

    float A2[DS], h[DS];
    float4 al[4];
    #pragma unroll
    for (int i = 0; i < 4; i++)
        al[i] = reinterpret_cast<const float4*>(A_log + (size_t)d * DS)[i];
    #pragma unroll
    for (int i = 0; i < 4; i++) {
        A2[4*i+0] = -__expf(al[i].x) * L2E;
        A2[4*i+1] = -__expf(al[i].y) * L2E;
        A2[4*i+2] = -__expf(al[i].z) * L2E;
        A2[4*i+3] = -__expf(al[i].w) * L2E;
    }
    const size_t ho = ((size_t)(b * CCH + c) * DI + d) * DS;
    #pragma unroll
    for (int n = 0; n < DS; n++) h[n] = Hin[ho + n];
    const float wdt = w_dt[d], bdt = b_dt[d], Dv = Dp[d];

    for (int t = 0; t < LCH; t++) {
        const float* sp = &sm[t * SMW];
        float Bv[DS], Cv[DS];
        #pragma unroll
        for (int i = 0; i < 4; i++) {
            float4 bv = *reinterpret_cast<const float4*>(sp + 4 + 4 * i);
            Bv[4*i+0] = bv.x; Bv[4*i+1] = bv.y; Bv[4*i+2] = bv.z; Bv[4*i+3] = bv.w;
            float4 cv = *reinterpret_cast<const float4*>(sp + 20 + 4 * i);
            Cv[4*i+0] = cv.x; Cv[4*i+1] = cv.y; Cv[4*i+2] = cv.z; Cv[4*i+3] = cv.w;
        }
        float pre = sp[0] * wdt + bdt;
        float dtv = (pre > 20.f) ? pre : __logf(1.f + __expf(pre));
        const size_t row = (size_t)(b * TT + c * LCH + t);
        float xv = bu2f(xls[t * 256 + tid]);
        float u = dtv * xv;
        float y = 0.f;
        #pragma unroll
        for (int n = 0; n < DS; n++) {
            h[n] = EXP2F(dtv * A2[n]) * h[n] + u * Bv[n];
            y += h[n] * Cv[n];
        }
        float z = bu2f(xz[row * (2 * DI) + DI + d]);
        float sz = z / (1.0f + __expf(-z));
        xcy[row * DI + d] = f2bu((y + Dv * xv) * sz);   // staged reads done; exclusive owner
    }
}

extern "C" void kernel_launch(void* const* d_in, const int* in_sizes, int n_in,
                              void* d_out, int out_size, void* d_ws, size_t ws_size,
                              hipStream_t stream) {
    // Input-order resolution by in_sizes signature (dict order confirmed).
    int ix, ig, ib, iWin, icw, icb, iWx, iwdt, ibdt, iAl, iD, iWo;
    if (n_in >= 12 && in_sizes[0] == 32768) {
        iAl = 0; iD = 1; iWin = 2; iWo = 3; iWx = 4; ibdt = 5;
        icb = 6; icw = 7; ib = 8; ig = 9; iwdt = 10; ix = 11;
    } else if (n_in >= 12 && in_sizes[0] == 2097152 && in_sizes[1] == 2048 && in_sizes[2] == 32768) {
        iWo = 0; iD = 1; iAl = 2; ibdt = 3; iwdt = 4; iWx = 5;
        icb = 6; icw = 7; iWin = 8; ib = 9; ig = 10; ix = 11;
    } else {
        ix = 0; ig = 1; ib = 2; iWin = 3; icw = 4; icb = 5;
        iWx = 6; iwdt = 7; ibdt = 8; iAl = 9; iD = 10; iWo = 11;
    }

    const float* x       = (const float*)d_in[ix];
    const float* ln_g    = (const float*)d_in[ig];
    const float* ln_b    = (const float*)d_in[ib];
    const float* W_in    = (const float*)d_in[iWin];
    const float* conv_w  = (const float*)d_in[icw];
    const float* conv_b  = (const float*)d_in[icb];
    const float* W_x     = (const float*)d_in[iWx];
    const float* w_dt    = (const float*)d_in[iwdt];
    const float* b_dt    = (const float*)d_in[ibdt];
    const float* A_log   = (const float*)d_in[iAl];
    const float* D_param = (const float*)d_in[iD];
    const float* W_out   = (const float*)d_in[iWo];
    float* out = (float*)d_out;   // fp32 output (verified R5)

    // Workspace layout (~50 MB):
    float* ssm  = (float*)d_ws;                     // MM*33 fp32
    u16*   xn   = (u16*)(ssm + (size_t)MM * 33);    // MM*DM bf16
    u16*   xz   = xn + (size_t)MM * DM;             // MM*2*DI bf16
    u16*   xcy  = xz + (size_t)MM * 2 * DI;         // MM*DI bf16 (xc, then y)
    float* F    = (float*)(xcy + (size_t)MM * DI);  // B*CCH*DI*DS fp32 (F, then carry-in)
    float* Sdt  = F + (size_t)BB * CCH * DI * DS;   // B*CCH*DI fp32
    u16*   Wi_b = (u16*)(Sdt + (size_t)BB * CCH * DI);      // 2*DI*DM bf16
    u16*   Wo_b = Wi_b + (size_t)2 * DI * DM;               // DM*DI bf16
    u16*   Wx_b = Wo_b + (size_t)DM * DI;                   // 33*DI bf16
    int*   cnt  = (int*)(Wx_b + (size_t)33 * DI);           // BB*8 ints

    // LN + all weight conversions + counter zeroing in ONE launch
    prep_kernel<<<MM + F2B_BLOCKS, 256, 0, stream>>>(x, ln_g, ln_b, xn, W_in, Wi_b,
                                                     W_out, Wo_b, W_x, Wx_b, cnt);

    // xz = xn @ W_in.T   (M=2048, N=4096, K=1024): 128x128 tiles, BK=64
    gemm1_mfma<<<dim3(4096 / 128, MM / 128), 256, 0, stream>>>(xn, Wi_b, xz, MM, 2 * DI, DM);

    // fused conv + SiLU + MFMA ssm projection (256 blocks)
    convproj_kernel<<<MM / PR, 256, 0, stream>>>(xz, conv_w, conv_b, Wx_b, xcy, ssm);

    // chunked scan: part1(+decoupled combine tail) -> part2(+gate)
    scan_part1<<<BB * CCH * (DI / 256), 256, 0, stream>>>(ssm, xcy, w_dt, b_dt, A_log,
                                                          F, Sdt, cnt);
    scan_part2<<<BB * CCH * (DI / 256), 256, 0, stream>>>(ssm, xz, xcy, w_dt, b_dt, A_log,
                                                          D_param, F);

    // out = x + y @ W_out.T   (M=2048, N=1024, K=2048): 64x64 tiles, BK=128
    gemm2_mfma<<<dim3(1024 / 64, MM / 64), 256, 0, stream>>>(xcy, Wo_b, out, x, MM, DM, DI);
}

// Round 11
// 195.778 us; speedup vs baseline: 1.5538x; 1.5538x over previous
//
#include <hip/hip_runtime.h>
#include <hip/hip_bf16.h>

#define DM 1024
#define DI 2048
#define DS 16
#define DC 4
#define BB 2
#define TT 1024
#define MM (BB*TT)   // 2048 rows
#define CCH 32       // scan chunks
#define LCH 32       // chunk length (TT/CCH)
#define PR 8         // rows per convproj block
#define SMW 36       // padded sm row (floats): 0=dt, 4..19=B, 20..35=C

typedef unsigned short u16;
typedef __attribute__((ext_vector_type(8))) short bf16x8;   // 8 bf16 (4 VGPRs)
typedef __attribute__((ext_vector_type(4))) float f32x4;    // 4 fp32 acc

#if __has_builtin(__builtin_amdgcn_exp2f)
#define EXP2F(x) __builtin_amdgcn_exp2f(x)
#else
#define EXP2F(x) exp2f(x)
#endif
#define L2E 1.44269504f

__device__ __forceinline__ float bu2f(u16 u) {
    union { unsigned int i; float f; } w; w.i = ((unsigned int)u) << 16; return w.f;
}
__device__ __forceinline__ u16 f2bu(float f) {  // round-to-nearest-even bf16
    union { float f; unsigned int u; } w; w.f = f;
    unsigned int r = w.u + 0x7fffu + ((w.u >> 16) & 1u);
    return (u16)(r >> 16);
}
// unpack element e (0..7) of a uint4 holding 8 bf16
__device__ __forceinline__ float upk(const uint4& v, int e) {
    unsigned int u;
    switch (e >> 1) { case 0: u = v.x; break; case 1: u = v.y; break;
                      case 2: u = v.z; break; default: u = v.w; }
    union { unsigned int i; float f; } w;
    w.i = (e & 1) ? (u & 0xffff0000u) : (u << 16);
    return w.f;
}

// ======= prep: LayerNorm (blocks 0..MM-1) + weight f32->bf16 (rest) ========
#define F2B_BLOCKS 6210
__global__ __launch_bounds__(256) void prep_kernel(const float* __restrict__ x,
                                                   const float* __restrict__ gamma,
                                                   const float* __restrict__ beta,
                                                   u16* __restrict__ xn,
                                                   const float* __restrict__ Wi,
                                                   u16* __restrict__ Wi_b,
                                                   const float* __restrict__ Wo,
                                                   u16* __restrict__ Wo_b,
                                                   const float* __restrict__ Wx,
                                                   u16* __restrict__ Wx_b) {
    const int tid = threadIdx.x;
    if (blockIdx.x >= MM) {
        const int n4W  = 2 * DI * DM / 4;
        const int n4Wo = DM * DI / 4;
        int i = (blockIdx.x - MM) * 256 + tid;
        const float* in; u16* out;
        if (i < n4W) { in = Wi; out = Wi_b; }
        else if (i < n4W + n4Wo) { in = Wo; out = Wo_b; i -= n4W; }
        else { in = Wx; out = Wx_b; i -= n4W + n4Wo; }
        float4 v = reinterpret_cast<const float4*>(in)[i];
        ushort4 o;
        o.x = f2bu(v.x); o.y = f2bu(v.y); o.z = f2bu(v.z); o.w = f2bu(v.w);
        reinterpret_cast<ushort4*>(out)[i] = o;
        return;
    }
    __shared__ float sbuf[8];
    const int row = blockIdx.x;
    float4 v = reinterpret_cast<const float4*>(x + (size_t)row * DM)[tid];

    float s = v.x + v.y + v.z + v.w;
    #pragma unroll
    for (int off = 32; off; off >>= 1) s += __shfl_down(s, off);
    if ((tid & 63) == 0) sbuf[tid >> 6] = s;
    __syncthreads();
    float mu = (sbuf[0] + sbuf[1] + sbuf[2] + sbuf[3]) * (1.0f / DM);
    __syncthreads();

    float d0 = v.x - mu, d1 = v.y - mu, d2 = v.z - mu, d3 = v.w - mu;
    float q = d0*d0 + d1*d1 + d2*d2 + d3*d3;
    #pragma unroll
    for (int off = 32; off; off >>= 1) q += __shfl_down(q, off);
    if ((tid & 63) == 0) sbuf[tid >> 6] = q;
    __syncthreads();
    float var = (sbuf[0] + sbuf[1] + sbuf[2] + sbuf[3]) * (1.0f / DM);
    float rstd = rsqrtf(var + 1e-5f);

    float4 g = reinterpret_cast<const float4*>(gamma)[tid];
    float4 b = reinterpret_cast<const float4*>(beta)[tid];
    ushort4 o;
    o.x = f2bu(d0 * rstd * g.x + b.x);
    o.y = f2bu(d1 * rstd * g.y + b.y);
    o.z = f2bu(d2 * rstd * g.z + b.z);
    o.w = f2bu(d3 * rstd * g.w + b.w);
    reinterpret_cast<ushort4*>(xn + (size_t)row * DM)[tid] = o;
}

// ========== MFMA GEMMs (NT), double-buffered, slot-XOR LDS swizzle =========
__device__ __forceinline__ void gl_lds(const u16* g, u16* lds) {
    __builtin_amdgcn_global_load_lds((const __attribute__((address_space(1))) void*)g,
                                     (__attribute__((address_space(3))) void*)lds,
                                     16, 0, 0);
}

// gemm1: 128x128 tile, BK=64 (two 32-k sub-tiles), 4 waves 2x2 (each 64x64).
// 512 blocks (2/CU), 64 KB LDS.
__global__ __launch_bounds__(256) void gemm1_mfma(const u16* __restrict__ A,
                                                  const u16* __restrict__ B,
                                                  u16* __restrict__ C,
                                                  int M, int N, int K) {
    __shared__ u16 As[2][2][128 * 32];   // [buf][kh] 32 KB
    __shared__ u16 Bs[2][2][128 * 32];   // 32 KB
    const int tid  = threadIdx.x;
    const int lane = tid & 63;
    const int w    = tid >> 6;
    const int wm   = (w >> 1) * 64, wn = (w & 1) * 64;
    const int m0   = blockIdx.y * 128, n0 = blockIdx.x * 128;

    const int srow = tid >> 2;           // 0..63
    const int sk   = (((tid & 3) ^ ((srow >> 1) & 3)) * 8);   // swizzled k-octet
    const u16* aP0 = A + (size_t)(m0 + srow) * K + sk;
    const u16* aP1 = aP0 + (size_t)64 * K;
    const u16* bP0 = B + (size_t)(n0 + srow) * K + sk;
    const u16* bP1 = bP0 + (size_t)64 * K;
    const int ldst = tid * 8;            // LINEAR dest, 16 B/thread

    const int fr = lane & 15, fq = (lane >> 4) * 8;

    #pragma unroll
    for (int kh = 0; kh < 2; kh++) {
        gl_lds(aP0 + kh * 32, &As[0][kh][ldst]); gl_lds(aP1 + kh * 32, &As[0][kh][2048 + ldst]);
        gl_lds(bP0 + kh * 32, &Bs[0][kh][ldst]); gl_lds(bP1 + kh * 32, &Bs[0][kh][2048 + ldst]);
    }
    __syncthreads();

    const int iters = K >> 6;            // 16
    f32x4 acc[4][4] = {};
    for (int it = 0; it < iters; it++) {
        const int cur = it & 1;
        const int kn = (it + 1) << 6;
        if (kn < K) {
            const int nb = cur ^ 1;
            #pragma unroll
            for (int kh = 0; kh < 2; kh++) {
                gl_lds(aP0 + kn + kh * 32, &As[nb][kh][ldst]);
                gl_lds(aP1 + kn + kh * 32, &As[nb][kh][2048 + ldst]);
                gl_lds(bP0 + kn + kh * 32, &Bs[nb][kh][ldst]);
                gl_lds(bP1 + kn + kh * 32, &Bs[nb][kh][2048 + ldst]);
            }
        }
        #pragma unroll
        for (int kh = 0; kh < 2; kh++) {
            bf16x8 af[4], bf[4];
            #pragma unroll
            for (int i = 0; i < 4; i++) {
                const int ra = wm + i * 16 + fr;
                af[i] = *reinterpret_cast<const bf16x8*>(
                    &As[cur][kh][ra * 32 + (fq ^ (((ra >> 1) & 3) << 3))]);
            }
            #pragma unroll
            for (int j = 0; j < 4; j++) {
                const int rb = wn + j * 16 + fr;
                bf[j] = *reinterpret_cast<const bf16x8*>(
                    &Bs[cur][kh][rb * 32 + (fq ^ (((rb >> 1) & 3) << 3))]);
            }
            #pragma unroll
            for (int i = 0; i < 4; i++)
                #pragma unroll
                for (int j = 0; j < 4; j++)
                    acc[i][j] = __builtin_amdgcn_mfma_f32_16x16x32_bf16(af[i], bf[j], acc[i][j], 0, 0, 0);
        }
        __syncthreads();
    }

    const int erow = (lane >> 4) * 4, ecol = lane & 15;
    #pragma unroll
    for (int i = 0; i < 4; i++)
        #pragma unroll
        for (int j = 0; j < 4; j++) {
            const int col = n0 + wn + j * 16 + ecol;
            #pragma unroll
            for (int r = 0; r < 4; r++) {
                const int row = m0 + wm + i * 16 + erow + r;
                C[(size_t)row * N + col] = f2bu(acc[i][j][r]);
            }
        }
}

// gemm2: 64x64 tile, BK=128 (four 32-k sub-tiles), 4 waves 2x2, +residual,
// fp32 out. 512 blocks (2/CU), 64 KB LDS. Same swizzle.
__global__ __launch_bounds__(256) void gemm2_mfma(const u16* __restrict__ A,
                                                  const u16* __restrict__ B,
                                                  float* __restrict__ C,
                                                  const float* __restrict__ resid,
                                                  int M, int N, int K) {
    __shared__ u16 As[2][4][64 * 32];   // 32 KB
    __shared__ u16 Bs[2][4][64 * 32];   // 32 KB
    const int tid  = threadIdx.x;
    const int lane = tid & 63;
    const int w    = tid >> 6;
    const int wm   = (w >> 1) * 32, wn = (w & 1) * 32;
    const int m0   = blockIdx.y * 64, n0 = blockIdx.x * 64;

    const int srow = tid >> 2;
    const int sk   = (((tid & 3) ^ ((srow >> 1) & 3)) * 8);
    const u16* aP = A + (size_t)(m0 + srow) * K + sk;
    const u16* bP = B + (size_t)(n0 + srow) * K + sk;
    const int ldst = tid * 8;

    const int fr = lane & 15, fq = (lane >> 4) * 8;

    #pragma unroll
    for (int kh = 0; kh < 4; kh++) {
        gl_lds(aP + kh * 32, &As[0][kh][ldst]);
        gl_lds(bP + kh * 32, &Bs[0][kh][ldst]);
    }
    __syncthreads();

    const int iters = K >> 7;            // 16
    f32x4 acc[2][2] = {};
    for (int it = 0; it < iters; it++) {
        const int cur = it & 1;
        const int kn = (it + 1) << 7;
        if (kn < K) {
            const int nb = cur ^ 1;
            #pragma unroll
            for (int kh = 0; kh < 4; kh++) {
                gl_lds(aP + kn + kh * 32, &As[nb][kh][ldst]);
                gl_lds(bP + kn + kh * 32, &Bs[nb][kh][ldst]);
            }
        }
        #pragma unroll
        for (int kh = 0; kh < 4; kh++) {
            bf16x8 af[2], bf[2];
            #pragma unroll
            for (int i = 0; i < 2; i++) {
                const int ra = wm + i * 16 + fr;
                af[i] = *reinterpret_cast<const bf16x8*>(
                    &As[cur][kh][ra * 32 + (fq ^ (((ra >> 1) & 3) << 3))]);
            }
            #pragma unroll
            for (int j = 0; j < 2; j++) {
                const int rb = wn + j * 16 + fr;
                bf[j] = *reinterpret_cast<const bf16x8*>(
                    &Bs[cur][kh][rb * 32 + (fq ^ (((rb >> 1) & 3) << 3))]);
            }
            #pragma unroll
            for (int i = 0; i < 2; i++)
                #pragma unroll
                for (int j = 0; j < 2; j++)
                    acc[i][j] = __builtin_amdgcn_mfma_f32_16x16x32_bf16(af[i], bf[j], acc[i][j], 0, 0, 0);
        }
        __syncthreads();
    }

    const int erow = (lane >> 4) * 4, ecol = lane & 15;
    #pragma unroll
    for (int i = 0; i < 2; i++)
        #pragma unroll
        for (int j = 0; j < 2; j++) {
            const int col = n0 + wn + j * 16 + ecol;
            #pragma unroll
            for (int r = 0; r < 4; r++) {
                const int row = m0 + wm + i * 16 + erow + r;
                C[(size_t)row * N + col] = acc[i][j][r] + resid[(size_t)row * N + col];
            }
        }
}

// ======= Fused depthwise conv(k=4) + SiLU + MFMA ssm projection ============
__global__ __launch_bounds__(256) void convproj_kernel(const u16* __restrict__ xz,
                                                       const float* __restrict__ cw,
                                                       const float* __restrict__ cb,
                                                       const u16* __restrict__ Wxb,
                                                       u16* __restrict__ xc,
                                                       float* __restrict__ ssm) {
    __shared__ u16 xs[64 * PR * 32];     // [kt][r][ko] 32 KB
    __shared__ float red[4][PR][48];     // 6 KB
    const int tid  = threadIdx.x;
    const int row0 = blockIdx.x * PR;
    const int t0   = row0 & (TT - 1);
    const int d0   = tid * 8;

    float4 w4[8];
    #pragma unroll
    for (int e = 0; e < 8; e++) w4[e] = reinterpret_cast<const float4*>(cw)[d0 + e];
    float bias[8];
    *reinterpret_cast<float4*>(&bias[0]) = reinterpret_cast<const float4*>(cb + d0)[0];
    *reinterpret_cast<float4*>(&bias[4]) = reinterpret_cast<const float4*>(cb + d0)[1];

    uint4 pk[PR + 3];
    #pragma unroll
    for (int j = 0; j < PR + 3; j++) {
        const int tr = t0 - 3 + j;
        if (tr >= 0)
            pk[j] = *reinterpret_cast<const uint4*>(xz + (size_t)(row0 - 3 + j) * (2 * DI) + d0);
        else
            pk[j] = make_uint4(0, 0, 0, 0);
    }

    const int kt_w = tid >> 2;
    const int ko_w = (tid & 3) * 8;
    #pragma unroll
    for (int r = 0; r < PR; r++) {
        u16 ob[8];
        #pragma unroll
        for (int e = 0; e < 8; e++) {
            float a = bias[e]
                    + upk(pk[r],     e) * w4[e].x
                    + upk(pk[r + 1], e) * w4[e].y
                    + upk(pk[r + 2], e) * w4[e].z
                    + upk(pk[r + 3], e) * w4[e].w;
            float sv = a / (1.0f + __expf(-a));
            ob[e] = f2bu(sv);
        }
        uint4 o;
        o.x = (unsigned)ob[0] | ((unsigned)ob[1] << 16);
        o.y = (unsigned)ob[2] | ((unsigned)ob[3] << 16);
        o.z = (unsigned)ob[4] | ((unsigned)ob[5] << 16);
        o.w = (unsigned)ob[6] | ((unsigned)ob[7] << 16);
        *reinterpret_cast<uint4*>(xc + (size_t)(row0 + r) * DI + d0) = o;
        *reinterpret_cast<uint4*>(&xs[kt_w * (PR * 32) + r * 32 + ko_w]) = o;
    }
    __syncthreads();

    const int lane = tid & 63, w = tid >> 6;
    const int fr = lane & 15, fq = (lane >> 4) * 8;
    const int kt0 = w * 16;
    const u16* b0p = Wxb + (size_t)(fr)      * DI + fq;
    const u16* b1p = Wxb + (size_t)(16 + fr) * DI + fq;
    const u16* b2p = Wxb + (size_t)32        * DI + fq;

    f32x4 acc0 = {}, acc1 = {}, acc2 = {};
    bf16x8 a_c = *reinterpret_cast<const bf16x8*>(&xs[kt0 * (PR * 32) + (fr & 7) * 32 + fq]);
    bf16x8 b0c = *reinterpret_cast<const bf16x8*>(b0p + (size_t)kt0 * 32);
    bf16x8 b1c = *reinterpret_cast<const bf16x8*>(b1p + (size_t)kt0 * 32);
    bf16x8 b2c = *reinterpret_cast<const bf16x8*>(b2p + (size_t)kt0 * 32);
    #pragma unroll
    for (int i = 0; i < 16; i++) {
        bf16x8 a_n, b0n, b1n, b2n;
        if (i < 15) {
            const int ktn = kt0 + i + 1;
            a_n = *reinterpret_cast<const bf16x8*>(&xs[ktn * (PR * 32) + (fr & 7) * 32 + fq]);
            b0n = *reinterpret_cast<const bf16x8*>(b0p + (size_t)ktn * 32);
            b1n = *reinterpret_cast<const bf16x8*>(b1p + (size_t)ktn * 32);
            b2n = *reinterpret_cast<const bf16x8*>(b2p + (size_t)ktn * 32);
        }
        acc0 = __builtin_amdgcn_mfma_f32_16x16x32_bf16(a_c, b0c, acc0, 0, 0, 0);
        acc1 = __builtin_amdgcn_mfma_f32_16x16x32_bf16(a_c, b1c, acc1, 0, 0, 0);
        acc2 = __builtin_amdgcn_mfma_f32_16x16x32_bf16(a_c, b2c, acc2, 0, 0, 0);
        if (i < 15) { a_c = a_n; b0c = b0n; b1c = b1n; b2c = b2n; }
    }
    const int erow = (lane >> 4) * 4, ecol = lane & 15;
    if (erow < PR) {
        #pragma unroll
        for (int r = 0; r < 4; r++) {
            red[w][erow + r][0 * 16 + ecol] = acc0[r];
            red[w][erow + r][1 * 16 + ecol] = acc1[r];
            red[w][erow + r][2 * 16 + ecol] = acc2[r];
        }
    }
    __syncthreads();

    // full coverage: all PR*33 = 264 cells via strided loop
    for (int idx = tid; idx < PR * 33; idx += 256) {
        const int rr = idx / 33, n = idx % 33;
        float s = red[0][rr][n] + red[1][rr][n] + red[2][rr][n] + red[3][rr][n];
        ssm[(size_t)(row0 + rr) * 33 + n] = s;
    }
}

// ======================= Chunked selective scan =============================
// sm staged into padded SMW=36 rows (0=dt, 4..19=B, 20..35=C) so per-t reads
// are 1 scalar + float4s instead of 33 scalar ds_read_b32.
__global__ __launch_bounds__(256) void scan_part1(const float* __restrict__ ssm,
                                                  const u16* __restrict__ xcy,
                                                  const float* __restrict__ w_dt,
                                                  const float* __restrict__ b_dt,
                                                  const float* __restrict__ A_log,
                                                  float* __restrict__ F,
                                                  float* __restrict__ Sdt) {
    __shared__ float sm[LCH * SMW];                // 4.6 KB padded
    __shared__ u16 xls[LCH * 256];                 // 16 KB
    const int tid = threadIdx.x;
    const int dt8 = blockIdx.x & 7;                // d-tile (DI/256 = 8)
    const int bc  = blockIdx.x >> 3;               // 0..63
    const int c   = bc & (CCH - 1);
    const int b   = bc >> 5;
    const int d   = dt8 * 256 + tid;

    const int base = ((b * TT) + c * LCH) * 33;
    for (int i = tid; i < LCH * 33; i += 256) {
        int t = i / 33, j = i % 33;                // slot: 0->0, j->j+3
        sm[t * SMW + (j == 0 ? 0 : j + 3)] = ssm[base + i];
    }
    const u16* xg = xcy + (size_t)(b * TT + c * LCH) * DI + dt8 * 256;
    for (int i = tid; i < LCH * 128; i += 256) {   // uint = 2 bf16
        int t = i >> 7, dp = i & 127;
        unsigned int v = *reinterpret_cast<const unsigned int*>(xg + (size_t)t * DI + dp * 2);
        *reinterpret_cast<unsigned int*>(&xls[t * 256 + dp * 2]) = v;
    }
    __syncthreads();

    float A2[DS], h[DS];
    float4 al[4];
    #pragma unroll
    for (int i = 0; i < 4; i++)
        al[i] = reinterpret_cast<const float4*>(A_log + (size_t)d * DS)[i];
    #pragma unroll
    for (int i = 0; i < 4; i++) {
        A2[4*i+0] = -__expf(al[i].x) * L2E;
        A2[4*i+1] = -__expf(al[i].y) * L2E;
        A2[4*i+2] = -__expf(al[i].z) * L2E;
        A2[4*i+3] = -__expf(al[i].w) * L2E;
    }
    #pragma unroll
    for (int n = 0; n < DS; n++) h[n] = 0.f;
    const float wdt = w_dt[d], bdt = b_dt[d];
    float sdt = 0.f;

    for (int t = 0; t < LCH; t++) {
        const float* sp = &sm[t * SMW];
        float Bv[DS];
        #pragma unroll
        for (int i = 0; i < 4; i++) {
            float4 bv = *reinterpret_cast<const float4*>(sp + 4 + 4 * i);
            Bv[4*i+0] = bv.x; Bv[4*i+1] = bv.y; Bv[4*i+2] = bv.z; Bv[4*i+3] = bv.w;
        }
        float pre = sp[0] * wdt + bdt;
        float dtv = (pre > 20.f) ? pre : __logf(1.f + __expf(pre));
        sdt += dtv;
        float xv = bu2f(xls[t * 256 + tid]);
        float u = dtv * xv;
        #pragma unroll
        for (int n = 0; n < DS; n++) h[n] = EXP2F(dtv * A2[n]) * h[n] + u * Bv[n];
    }
    const size_t fo = ((size_t)(b * CCH + c) * DI + d) * DS;
    #pragma unroll
    for (int n = 0; n < DS; n++) F[fo + n] = h[n];
    Sdt[(b * CCH + c) * DI + d] = sdt;
}

// In-place: on exit F[c] holds the CARRY-IN state for chunk c.
// Prefetch-then-chain: all 64 loads issued independently (one latency
// exposure), exps precomputed (independent), chain is 32 pure FMAs.
__global__ __launch_bounds__(256) void scan_combine(float* __restrict__ F,
                                                    const float* __restrict__ Sdt,
                                                    const float* __restrict__ A_log) {
    const int g = blockIdx.x * 256 + threadIdx.x;  // B*DI*DS = 65536
    const int n = g & (DS - 1);
    const int d = (g >> 4) & (DI - 1);
    const int b = g >> 15;
    const float A2 = -__expf(A_log[d * DS + n]) * L2E;

    float f[CCH], q[CCH];
    #pragma unroll
    for (int c = 0; c < CCH; c++) {
        const size_t o = ((size_t)(b * CCH + c) * DI + d) * DS + n;
        f[c] = F[o];
        q[c] = Sdt[(b * CCH + c) * DI + d];
    }
    #pragma unroll
    for (int c = 0; c < CCH; c++) q[c] = EXP2F(q[c] * A2);

    float h = 0.f, hc[CCH];
    #pragma unroll
    for (int c = 0; c < CCH; c++) {
        hc[c] = h;
        h = q[c] * h + f[c];
    }
    #pragma unroll
    for (int c = 0; c < CCH; c++) {
        const size_t o = ((size_t)(b * CCH + c) * DI + d) * DS + n;
        F[o] = hc[c];
    }
}

__global__ __launch_bounds__(256) void scan_part2(const float* __restrict__ ssm,
                                                  const u16* __restrict__ xz,
                                                  u16* __restrict__ xcy,
                                                  const float* __restrict__ w_dt,
                                                  const float* __restrict__ b_dt,
                                                  const float* __restrict__ A_log,
                                                  const float* __restrict__ Dp,
                                                  const float* __restrict__ Hin) {
    __shared__ float sm[LCH * SMW];
    __shared__ u16 xls[LCH * 256];
    const int tid = threadIdx.x;
    const int dt8 = blockIdx.x & 7;
    const int bc  = blockIdx.x >> 3;
    const int c   = bc & (CCH - 1);
    const int b   = bc >> 5;
    const int d   = dt8 * 256 + tid;

    const int base = ((b * TT) + c * LCH) * 33;
    for (int i = tid; i < LCH * 33; i += 256) {
        int t = i / 33, j = i % 33;
        sm[t * SMW + (j == 0 ? 0 : j + 3)] = ssm[base + i];
    }
    const u16* xg = xcy + (size_t)(b * TT + c * LCH) * DI + dt8 * 256;
    for (int i = tid; i < LCH * 128; i += 256) {
        int t = i >> 7, dp = i & 127;
        unsigned int v = *reinterpret_cast<const unsigned int*>(xg + (size_t)t * DI + dp * 2);
        *reinterpret_cast<unsigned int*>(&xls[t * 256 + dp * 2]) = v;
    }
    __syncthreads();

    float A2[DS], h[DS];
    float4 al[4];
    #pragma unroll
    for (int i = 0; i < 4; i++)
        al[i] = reinterpret_cast<const float4*>(A_log + (size_t)d * DS)[i];
    #pragma unroll
    for (int i = 0; i < 4; i++) {
        A2[4*i+0] = -__expf(al[i].x) * L2E;
        A2[4*i+1] = -__expf(al[i].y) * L2E;
        A2[4*i+2] = -__expf(al[i].z) * L2E;
        A2[4*i+3] = -__expf(al[i].w) * L2E;
    }
    const size_t ho = ((size_t)(b * CCH + c) * DI + d) * DS;
    #pragma unroll
    for (int n = 0; n < DS; n++) h[n] = Hin[ho + n];
    const float wdt = w_dt[d], bdt = b_dt[d], Dv = Dp[d];

    for (int t = 0; t < LCH; t++) {
        const float* sp = &sm[t * SMW];
        float Bv[DS], Cv[DS];
        #pragma unroll
        for (int i = 0; i < 4; i++) {
            float4 bv = *reinterpret_cast<const float4*>(sp + 4 + 4 * i);
            Bv[4*i+0] = bv.x; Bv[4*i+1] = bv.y; Bv[4*i+2] = bv.z; Bv[4*i+3] = bv.w;
            float4 cv = *reinterpret_cast<const float4*>(sp + 20 + 4 * i);
            Cv[4*i+0] = cv.x; Cv[4*i+1] = cv.y; Cv[4*i+2] = cv.z; Cv[4*i+3] = cv.w;
        }
        float pre = sp[0] * wdt + bdt;
        float dtv = (pre > 20.f) ? pre : __logf(1.f + __expf(pre));
        const size_t row = (size_t)(b * TT + c * LCH + t);
        float xv = bu2f(xls[t * 256 + tid]);
        float u = dtv * xv;
        float y = 0.f;
        #pragma unroll
        for (int n = 0; n < DS; n++) {
            h[n] = EXP2F(dtv * A2[n]) * h[n] + u * Bv[n];
            y += h[n] * Cv[n];
        }
        float z = bu2f(xz[row * (2 * DI) + DI + d]);
        float sz = z / (1.0f + __expf(-z));
        xcy[row * DI + d] = f2bu((y + Dv * xv) * sz);   // staged reads done; exclusive owner
    }
}

extern "C" void kernel_launch(void* const* d_in, const int* in_sizes, int n_in,
                              void* d_out, int out_size, void* d_ws, size_t ws_size,
                              hipStream_t stream) {
    // Input-order resolution by in_sizes signature (dict order confirmed).
    int ix, ig, ib, iWin, icw, icb, iWx, iwdt, ibdt, iAl, iD, iWo;
    if (n_in >= 12 && in_sizes[0] == 32768) {
        iAl = 0; iD = 1; iWin = 2; iWo = 3; iWx = 4; ibdt = 5;
        icb = 6; icw = 7; ib = 8; ig = 9; iwdt = 10; ix = 11;
    } else if (n_in >= 12 && in_sizes[0] == 2097152 && in_sizes[1] == 2048 && in_sizes[2] == 32768) {
        iWo = 0; iD = 1; iAl = 2; ibdt = 3; iwdt = 4; iWx = 5;
        icb = 6; icw = 7; iWin = 8; ib = 9; ig = 10; ix = 11;
    } else {
        ix = 0; ig = 1; ib = 2; iWin = 3; icw = 4; icb = 5;
        iWx = 6; iwdt = 7; ibdt = 8; iAl = 9; iD = 10; iWo = 11;
    }

    const float* x       = (const float*)d_in[ix];
    const float* ln_g    = (const float*)d_in[ig];
    const float* ln_b    = (const float*)d_in[ib];
    const float* W_in    = (const float*)d_in[iWin];
    const float* conv_w  = (const float*)d_in[icw];
    const float* conv_b  = (const float*)d_in[icb];
    const float* W_x     = (const float*)d_in[iWx];
    const float* w_dt    = (const float*)d_in[iwdt];
    const float* b_dt    = (const float*)d_in[ibdt];
    const float* A_log   = (const float*)d_in[iAl];
    const float* D_param = (const float*)d_in[iD];
    const float* W_out   = (const float*)d_in[iWo];
    float* out = (float*)d_out;   // fp32 output (verified R5)

    // Workspace layout (~49.5 MB):
    float* ssm  = (float*)d_ws;                     // MM*33 fp32
    u16*   xn   = (u16*)(ssm + (size_t)MM * 33);    // MM*DM bf16
    u16*   xz   = xn + (size_t)MM * DM;             // MM*2*DI bf16
    u16*   xcy  = xz + (size_t)MM * 2 * DI;         // MM*DI bf16 (xc, then y)
    float* F    = (float*)(xcy + (size_t)MM * DI);  // B*CCH*DI*DS fp32 (F, then Hin in place)
    float* Sdt  = F + (size_t)BB * CCH * DI * DS;   // B*CCH*DI fp32
    u16*   Wi_b = (u16*)(Sdt + (size_t)BB * CCH * DI);      // 2*DI*DM bf16
    u16*   Wo_b = Wi_b + (size_t)2 * DI * DM;               // DM*DI bf16
    u16*   Wx_b = Wo_b + (size_t)DM * DI;                   // 33*DI bf16

    // LN + all weight conversions in ONE launch
    prep_kernel<<<MM + F2B_BLOCKS, 256, 0, stream>>>(x, ln_g, ln_b, xn, W_in, Wi_b,
                                                     W_out, Wo_b, W_x, Wx_b);

    // xz = xn @ W_in.T   (M=2048, N=4096, K=1024): 128x128 tiles, BK=64
    gemm1_mfma<<<dim3(4096 / 128, MM / 128), 256, 0, stream>>>(xn, Wi_b, xz, MM, 2 * DI, DM);

    // fused conv + SiLU + MFMA ssm projection (256 blocks)
    convproj_kernel<<<MM / PR, 256, 0, stream>>>(xz, conv_w, conv_b, Wx_b, xcy, ssm);

    // chunked scan: part1 -> combine(in place) -> part2(+gate)
    scan_part1<<<BB * CCH * (DI / 256), 256, 0, stream>>>(ssm, xcy, w_dt, b_dt, A_log, F, Sdt);
    scan_combine<<<(BB * DI * DS) / 256, 256, 0, stream>>>(F, Sdt, A_log);
    scan_part2<<<BB * CCH * (DI / 256), 256, 0, stream>>>(ssm, xz, xcy, w_dt, b_dt, A_log, D_param, F);

    // out = x + y @ W_out.T   (M=2048, N=1024, K=2048): 64x64 tiles, BK=128
    gemm2_mfma<<<dim3(1024 / 64, MM / 64), 256, 0, stream>>>(xcy, Wo_b, out, x, MM, DM, DI);
}